// Round 3
// baseline (203.339 us; speedup 1.0000x reference)
//
#include <hip/hip_runtime.h>
#include <math.h>
#include <limits.h>

#define kB 4
#define kC 8
#define kH 384
#define kW 384
#define kCH (kC * kH)   // 3072
#define kIN (2 * kCH)   // 6144
#define kNC 18
#define kMID (kW / 2)

#define NCH 32                // row chunks (32 -> 96-row chunks, 4x block parallelism)
#define RPC (kCH / NCH)       // 96 rows per chunk
#define NGRP 48               // column groups of 8
#define kN (kB * kW * kNC)    // 27648 floats per dense P array

#define E18(M) M(0) M(1) M(2) M(3) M(4) M(5) M(6) M(7) M(8) M(9) M(10) M(11) M(12) M(13) M(14) M(15) M(16) M(17)
#define E3(M) M(0) M(1) M(2)

// Ballot-based faithful left/right from acquired_mask.
// right = kMID + first i in [0,192) with am[kMID+i] < 1 (0 if none)
// left  = 1 + first i in [0,192) with am[kMID-1-i] < 1 (0 if none)
__device__ __forceinline__ void mask_bounds(const float* __restrict__ amb,
                                            int lane, int* left, int* right) {
    unsigned long long mR0 = __ballot(amb[kMID + lane] < 1.0f);
    unsigned long long mR1 = __ballot(amb[kMID + 64 + lane] < 1.0f);
    unsigned long long mR2 = __ballot(amb[kMID + 128 + lane] < 1.0f);
    unsigned long long mL0 = __ballot(amb[kMID - 1 - lane] < 1.0f);
    unsigned long long mL1 = __ballot(amb[kMID - 65 - lane] < 1.0f);
    unsigned long long mL2 = __ballot(amb[kMID - 129 - lane] < 1.0f);
    int candR = mR0 ? __builtin_ctzll(mR0)
              : (mR1 ? 64 + __builtin_ctzll(mR1)
              : (mR2 ? 128 + __builtin_ctzll(mR2) : 0));
    int candL = mL0 ? __builtin_ctzll(mL0)
              : (mL1 ? 64 + __builtin_ctzll(mL1)
              : (mL2 ? 128 + __builtin_ctzll(mL2) : 0));
    *left  = candL + 1;
    *right = kMID + candR;
}

// n-th set bit (0-based) across a 384-bit mask in 6 u64 words; -1 if none.
__device__ __forceinline__ int nth_set(const unsigned long long* m, int n) {
#pragma unroll
    for (int j = 0; j < 6; ++j) {
        int p = __popcll(m[j]);
        if (n < p) {
            unsigned long long x = m[j];
            for (int t = 0; t < n; ++t) x &= (x - 1);   // drop n lowest set bits
            return 64 * j + (int)__builtin_ctzll(x);
        }
        n -= p;
    }
    return -1;
}

// --------------------------------------------------------------------------
// K1: grid (48 col-groups, 64 = chunk|pass, B). 256 threads = 8 cols x 32 rows,
// 3 row-iterations each (96-row chunk). 32 chunks -> 1280 active blocks
// (vs 320 at NCH=8): ~5 blocks/CU so HBM/staging latency is TLP-hidden.
// LDS only ~10KB/block. Scalar W1 staging (R1-proven, coalesced 256B/wave).
// pass 0 = acquired band columns; pass 1 = acquiring columns, ballot-compacted.
// Fused output zero-fill for qm==0 elements.
// --------------------------------------------------------------------------
__global__ __launch_bounds__(256)
void proj_kernel(const float* __restrict__ acquired,
                 const float* __restrict__ acquiring,
                 const float* __restrict__ am,
                 const float* __restrict__ qm,
                 const float* __restrict__ W1,
                 float* __restrict__ Pq_part, float* __restrict__ Pa_part,
                 float* __restrict__ out) {
    int g = blockIdx.x;
    int chunk = blockIdx.y & (NCH - 1);
    int pass = blockIdx.y >> 5;        // 0 = acquired (band), 1 = acquiring
    int b = blockIdx.z;
    int tid = threadIdx.x;
    int r0 = chunk * RPC;

    // ---- fused output zero-fill (poison-safe: pair_kernel writes qm>0 cols)
    {
        int flatB = (blockIdx.z * gridDim.y + blockIdx.y) * gridDim.x + blockIdx.x;
        int gid = flatB * 256 + tid;
        if (gid < kB * kH * kW) {
            int w = gid % kW;
            int ob = gid / (kH * kW);
            if (!(qm[ob * kW + w] > 0.0f)) out[gid] = 0.0f;
        }
    }

    int lane = tid & 63;
    int c8 = tid & 7, r32 = tid >> 3;
    int wave = tid >> 6;

    __shared__ float sW[RPC][20];        // 7680 B; 80B rows keep 16B alignment
    __shared__ float sRed[4][8][kNC];    // 2304 B
    __shared__ int sCol[8];

    int wcol;                            // this thread's source column
    bool slot_ok;
    if (pass == 0) {
        int left, right;
        mask_bounds(am + b * kW, lane, &left, &right);
        int w0 = g * 8;
        if (!((left < w0 + 8) && (right > w0))) return;
        wcol = w0 + c8;
        slot_ok = true;                  // pair reads only [left,right)
    } else {
        unsigned long long qmm[6];
#pragma unroll
        for (int j = 0; j < 6; ++j)
            qmm[j] = __ballot(qm[b * kW + 64 * j + lane] > 0.0f);
        int totp = 0;
#pragma unroll
        for (int j = 0; j < 6; ++j) totp += __popcll(qmm[j]);
        if (8 * g >= totp) return;       // no active column in this group
        int found = nth_set(qmm, 8 * g + c8);
        slot_ok = (found >= 0);
        wcol = slot_ok ? found : 0;      // dummy col 0 for inactive slots
    }
    if (tid < 8) sCol[tid] = slot_ok ? wcol : -1;

    const float* ks = (pass == 0) ? acquired : acquiring;
    const float* w1 = (pass == 0) ? (W1 + kCH) : W1;  // acquired->W1[:,CH:], acquiring->W1[:,:CH]

    // ---- hoist all k-space loads (rows r32 + 32*it), coalesced 64B/row
    const float* colp = ks + ((size_t)(b * kCH + r0 + r32) * kW + wcol) * 2;
#define KLOAD(it) const float2 v##it = *reinterpret_cast<const float2*>(colp + (size_t)(it) * 32 * kW * 2);
    E3(KLOAD)

    // ---- stage W1 chunk, scalar coalesced loads (overlap with k-loads in flight)
    for (int t = tid; t < kNC * RPC; t += 256) {
        int j = t / RPC, i = t - j * RPC;
        sW[i][j] = w1[j * kIN + r0 + i];
    }
    __syncthreads();

#define KMAG(it) const float f##it = sqrtf(v##it.x * v##it.x + v##it.y * v##it.y);
    E3(KMAG)

#define PDECL(j) float a##j = 0.0f;
    E18(PDECL)

#define ROWF(it) { \
        const float* row = &sW[r32 + 32 * (it)][0]; \
        const float4 q0 = *reinterpret_cast<const float4*>(row); \
        const float4 q1 = *reinterpret_cast<const float4*>(row + 4); \
        const float4 q2 = *reinterpret_cast<const float4*>(row + 8); \
        const float4 q3 = *reinterpret_cast<const float4*>(row + 12); \
        const float2 q4 = *reinterpret_cast<const float2*>(row + 16); \
        const float f = f##it; \
        a0  = fmaf(f, q0.x, a0);  a1  = fmaf(f, q0.y, a1);  \
        a2  = fmaf(f, q0.z, a2);  a3  = fmaf(f, q0.w, a3);  \
        a4  = fmaf(f, q1.x, a4);  a5  = fmaf(f, q1.y, a5);  \
        a6  = fmaf(f, q1.z, a6);  a7  = fmaf(f, q1.w, a7);  \
        a8  = fmaf(f, q2.x, a8);  a9  = fmaf(f, q2.y, a9);  \
        a10 = fmaf(f, q2.z, a10); a11 = fmaf(f, q2.w, a11); \
        a12 = fmaf(f, q3.x, a12); a13 = fmaf(f, q3.y, a13); \
        a14 = fmaf(f, q3.z, a14); a15 = fmaf(f, q3.w, a15); \
        a16 = fmaf(f, q4.x, a16); a17 = fmaf(f, q4.y, a17); }
    E3(ROWF)

    // reduce lanes with stride 8 (same column) within the wave
#define WRED(j) { a##j += __shfl_down(a##j, 32, 64); a##j += __shfl_down(a##j, 16, 64); \
                  a##j += __shfl_down(a##j, 8, 64); }
    E18(WRED)
    if (lane < 8) {
#define SSTORE(j) sRed[wave][lane][j] = a##j;
        E18(SSTORE)
    }
    __syncthreads();
    if (tid < 8 * kNC) {
        int c = tid / kNC, j = tid - c * kNC;
        int wc = sCol[c];
        if (wc >= 0) {
            float s = sRed[0][c][j] + sRed[1][c][j] + sRed[2][c][j] + sRed[3][c][j];
            float* Pp = (pass == 0) ? Pa_part : Pq_part;
            Pp[((size_t)chunk * kB * kW + (size_t)b * kW + wc) * kNC + j] = s;
        }
    }
}

// --------------------------------------------------------------------------
// K2: per acquiring column wi: heat = mean over wc in [left,right) of the
// 3-layer MLP + sigmoid. Fuses the 32-chunk partial reduce (coalesced LDS
// staging of Pa; 19-float padded rows -> conflict-free) and the output
// column broadcast. Ballot mask bounds, no barrier-tree.
// --------------------------------------------------------------------------
__global__ __launch_bounds__(256)
void pair_kernel(const float* __restrict__ Pq_part, const float* __restrict__ Pa_part,
                 const float* __restrict__ am, const float* __restrict__ qmask,
                 const float* __restrict__ b1, const float* __restrict__ W2,
                 const float* __restrict__ b2, const float* __restrict__ W3,
                 const float* __restrict__ b3, const float* __restrict__ W4,
                 const float* __restrict__ b4, float* __restrict__ out) {
    int wi = blockIdx.x, b = blockIdx.y, tid = threadIdx.x;
    if (!(qmask[b * kW + wi] > 0.0f)) return;

    int lane = tid & 63, wave = tid >> 6;
    int left, right;
    mask_bounds(am + b * kW, lane, &left, &right);
    int span = right - left;

    __shared__ float sPa[kW][19];                               // 29184 B, pad 19 -> conflict-free
    __shared__ float2 sW2[kNC * kNC / 2], sW3[kNC * kNC / 2];   // row-major pairs
    __shared__ float sW4[kNC], sb1[kNC], sb2[kNC], sb3[kNC], sPq[kNC];
    __shared__ float sb4s, wred[4], sHeat;

    if (tid < kNC * kNC / 2) {
        sW2[tid] = reinterpret_cast<const float2*>(W2)[tid];
        sW3[tid] = reinterpret_cast<const float2*>(W3)[tid];
    }
    if (tid >= 192 && tid < 192 + kNC) {
        int j = tid - 192;
        float s = 0.0f;
#pragma unroll
        for (int c = 0; c < NCH; ++c)
            s += Pq_part[((size_t)c * kB * kW + (size_t)b * kW + wi) * kNC + j];
        sPq[j] = s;
        sW4[j] = W4[j]; sb1[j] = b1[j]; sb2[j] = b2[j]; sb3[j] = b3[j];
    }
    if (tid == 255) sb4s = b4[0];

    // fused chunk-reduce: stage summed Pa[left..right) into LDS, coalesced;
    // all 32 partial loads independent and in flight (L2-resident).
    for (int t = tid; t < span * kNC; t += 256) {
        int k = t / kNC, j = t - k * kNC;
        float s = 0.0f;
#pragma unroll
        for (int c = 0; c < NCH; ++c)
            s += Pa_part[((size_t)c * kB * kW + (size_t)b * kW + (left + k)) * kNC + j];
        sPa[k][j] = s;
    }
    __syncthreads();

#define DOT2(S, k, v) (S[(k)*9+0].x*v##0  + S[(k)*9+0].y*v##1  + \
                       S[(k)*9+1].x*v##2  + S[(k)*9+1].y*v##3  + \
                       S[(k)*9+2].x*v##4  + S[(k)*9+2].y*v##5  + \
                       S[(k)*9+3].x*v##6  + S[(k)*9+3].y*v##7  + \
                       S[(k)*9+4].x*v##8  + S[(k)*9+4].y*v##9  + \
                       S[(k)*9+5].x*v##10 + S[(k)*9+5].y*v##11 + \
                       S[(k)*9+6].x*v##12 + S[(k)*9+6].y*v##13 + \
                       S[(k)*9+7].x*v##14 + S[(k)*9+7].y*v##15 + \
                       S[(k)*9+8].x*v##16 + S[(k)*9+8].y*v##17)

    float ssum = 0.0f;
    for (int k = tid; k < span; k += 256) {
        const float* pa = &sPa[k][0];
#define L1(j) float x##j = fmaxf(sPq[j] + sb1[j] + pa[j], 0.0f);
        E18(L1)
        asm volatile("" ::: "memory");
#define L2(k) float y##k = fmaxf(sb2[k] + DOT2(sW2, k, x), 0.0f);
        E18(L2)
        asm volatile("" ::: "memory");
#define L3(k) float z##k = fmaxf(sb3[k] + DOT2(sW3, k, y), 0.0f);
        E18(L3)
        asm volatile("" ::: "memory");
        float t = sb4s +
            (sW4[0]*z0 + sW4[1]*z1 + sW4[2]*z2 + sW4[3]*z3 + sW4[4]*z4 + sW4[5]*z5 +
             sW4[6]*z6 + sW4[7]*z7 + sW4[8]*z8 + sW4[9]*z9 + sW4[10]*z10 + sW4[11]*z11 +
             sW4[12]*z12 + sW4[13]*z13 + sW4[14]*z14 + sW4[15]*z15 + sW4[16]*z16 + sW4[17]*z17);
        ssum += 1.0f / (1.0f + expf(-t));
    }

    ssum += __shfl_down(ssum, 32, 64); ssum += __shfl_down(ssum, 16, 64);
    ssum += __shfl_down(ssum,  8, 64); ssum += __shfl_down(ssum,  4, 64);
    ssum += __shfl_down(ssum,  2, 64); ssum += __shfl_down(ssum,  1, 64);
    if (lane == 0) wred[wave] = ssum;
    __syncthreads();
    if (tid == 0)
        sHeat = (wred[0] + wred[1] + wred[2] + wred[3]) / (float)span;
    __syncthreads();

    // fused output broadcast for this acquiring column
    float hv = sHeat;
    for (int h = tid; h < kH; h += 256)
        out[((size_t)b * kH + h) * kW + wi] = hv;
}

extern "C" void kernel_launch(void* const* d_in, const int* in_sizes, int n_in,
                              void* d_out, int out_size, void* d_ws, size_t ws_size,
                              hipStream_t stream) {
    const float* acquired       = (const float*)d_in[0];
    const float* acquiring      = (const float*)d_in[1];
    const float* acquired_mask  = (const float*)d_in[2];
    const float* acquiring_mask = (const float*)d_in[3];
    const float* W1 = (const float*)d_in[4];
    const float* b1 = (const float*)d_in[5];
    const float* W2 = (const float*)d_in[6];
    const float* b2 = (const float*)d_in[7];
    const float* W3 = (const float*)d_in[8];
    const float* b3 = (const float*)d_in[9];
    const float* W4 = (const float*)d_in[10];
    const float* b4 = (const float*)d_in[11];
    float* out = (float*)d_out;

    float* Pa_part = (float*)d_ws;                 // NCH * kN = 3.5 MB
    float* Pq_part = Pa_part + (size_t)NCH * kN;   // NCH * kN

    proj_kernel<<<dim3(NGRP, 2 * NCH, kB), 256, 0, stream>>>(
        acquired, acquiring, acquired_mask, acquiring_mask, W1, Pq_part, Pa_part, out);
    pair_kernel<<<dim3(kW, kB), 256, 0, stream>>>(
        Pq_part, Pa_part, acquired_mask, acquiring_mask,
        b1, W2, b2, W3, b3, W4, b4, out);
}

// Round 4
// 152.936 us; speedup vs baseline: 1.3296x; 1.3296x over previous
//
#include <hip/hip_runtime.h>
#include <math.h>
#include <limits.h>

#define kB 4
#define kC 8
#define kH 384
#define kW 384
#define kCH (kC * kH)   // 3072
#define kIN (2 * kCH)   // 6144
#define kNC 18
#define kMID (kW / 2)

#define NCH 32                // row chunks (96-row chunks, high block parallelism)
#define RPC (kCH / NCH)       // 96 rows per chunk
#define NGRP 48               // column groups of 8
#define kN (kB * kW * kNC)    // 27648 floats per dense P array

#define E18(M) M(0) M(1) M(2) M(3) M(4) M(5) M(6) M(7) M(8) M(9) M(10) M(11) M(12) M(13) M(14) M(15) M(16) M(17)
#define E3(M) M(0) M(1) M(2)

// Ballot-based faithful left/right from acquired_mask.
__device__ __forceinline__ void mask_bounds(const float* __restrict__ amb,
                                            int lane, int* left, int* right) {
    unsigned long long mR0 = __ballot(amb[kMID + lane] < 1.0f);
    unsigned long long mR1 = __ballot(amb[kMID + 64 + lane] < 1.0f);
    unsigned long long mR2 = __ballot(amb[kMID + 128 + lane] < 1.0f);
    unsigned long long mL0 = __ballot(amb[kMID - 1 - lane] < 1.0f);
    unsigned long long mL1 = __ballot(amb[kMID - 65 - lane] < 1.0f);
    unsigned long long mL2 = __ballot(amb[kMID - 129 - lane] < 1.0f);
    int candR = mR0 ? __builtin_ctzll(mR0)
              : (mR1 ? 64 + __builtin_ctzll(mR1)
              : (mR2 ? 128 + __builtin_ctzll(mR2) : 0));
    int candL = mL0 ? __builtin_ctzll(mL0)
              : (mL1 ? 64 + __builtin_ctzll(mL1)
              : (mL2 ? 128 + __builtin_ctzll(mL2) : 0));
    *left  = candL + 1;
    *right = kMID + candR;
}

// n-th set bit (0-based) across a 384-bit mask in 6 u64 words; -1 if none.
__device__ __forceinline__ int nth_set(const unsigned long long* m, int n) {
#pragma unroll
    for (int j = 0; j < 6; ++j) {
        int p = __popcll(m[j]);
        if (n < p) {
            unsigned long long x = m[j];
            for (int t = 0; t < n; ++t) x &= (x - 1);   // drop n lowest set bits
            return 64 * j + (int)__builtin_ctzll(x);
        }
        n -= p;
    }
    return -1;
}

// --------------------------------------------------------------------------
// K1 (unchanged from R3): grid (48 col-groups, 64 = chunk|pass, B).
// 256 threads = 8 cols x 32 rows, 3 row-iters (96-row chunk). ~6K active
// blocks -> ~24/CU, LDS 10KB. Scalar coalesced W1 staging.
// pass 0 = acquired band cols; pass 1 = acquiring cols, ballot-compacted.
// Fused output zero-fill for qm==0 elements.
// --------------------------------------------------------------------------
__global__ __launch_bounds__(256)
void proj_kernel(const float* __restrict__ acquired,
                 const float* __restrict__ acquiring,
                 const float* __restrict__ am,
                 const float* __restrict__ qm,
                 const float* __restrict__ W1,
                 float* __restrict__ Pq_part, float* __restrict__ Pa_part,
                 float* __restrict__ out) {
    int g = blockIdx.x;
    int chunk = blockIdx.y & (NCH - 1);
    int pass = blockIdx.y >> 5;        // 0 = acquired (band), 1 = acquiring
    int b = blockIdx.z;
    int tid = threadIdx.x;
    int r0 = chunk * RPC;

    // ---- fused output zero-fill (poison-safe: pair_kernel writes qm>0 cols)
    {
        int flatB = (blockIdx.z * gridDim.y + blockIdx.y) * gridDim.x + blockIdx.x;
        int gid = flatB * 256 + tid;
        if (gid < kB * kH * kW) {
            int w = gid % kW;
            int ob = gid / (kH * kW);
            if (!(qm[ob * kW + w] > 0.0f)) out[gid] = 0.0f;
        }
    }

    int lane = tid & 63;
    int c8 = tid & 7, r32 = tid >> 3;
    int wave = tid >> 6;

    __shared__ float sW[RPC][20];        // 7680 B
    __shared__ float sRed[4][8][kNC];    // 2304 B
    __shared__ int sCol[8];

    int wcol;                            // this thread's source column
    bool slot_ok;
    if (pass == 0) {
        int left, right;
        mask_bounds(am + b * kW, lane, &left, &right);
        int w0 = g * 8;
        if (!((left < w0 + 8) && (right > w0))) return;
        wcol = w0 + c8;
        slot_ok = true;                  // pair reads only [left,right)
    } else {
        unsigned long long qmm[6];
#pragma unroll
        for (int j = 0; j < 6; ++j)
            qmm[j] = __ballot(qm[b * kW + 64 * j + lane] > 0.0f);
        int totp = 0;
#pragma unroll
        for (int j = 0; j < 6; ++j) totp += __popcll(qmm[j]);
        if (8 * g >= totp) return;       // no active column in this group
        int found = nth_set(qmm, 8 * g + c8);
        slot_ok = (found >= 0);
        wcol = slot_ok ? found : 0;      // dummy col 0 for inactive slots
    }
    if (tid < 8) sCol[tid] = slot_ok ? wcol : -1;

    const float* ks = (pass == 0) ? acquired : acquiring;
    const float* w1 = (pass == 0) ? (W1 + kCH) : W1;  // acquired->W1[:,CH:], acquiring->W1[:,:CH]

    // ---- hoist all k-space loads (rows r32 + 32*it), coalesced 64B/row
    const float* colp = ks + ((size_t)(b * kCH + r0 + r32) * kW + wcol) * 2;
#define KLOAD(it) const float2 v##it = *reinterpret_cast<const float2*>(colp + (size_t)(it) * 32 * kW * 2);
    E3(KLOAD)

    // ---- stage W1 chunk, scalar coalesced loads (overlap with k-loads in flight)
    for (int t = tid; t < kNC * RPC; t += 256) {
        int j = t / RPC, i = t - j * RPC;
        sW[i][j] = w1[j * kIN + r0 + i];
    }
    __syncthreads();

#define KMAG(it) const float f##it = sqrtf(v##it.x * v##it.x + v##it.y * v##it.y);
    E3(KMAG)

#define PDECL(j) float a##j = 0.0f;
    E18(PDECL)

#define ROWF(it) { \
        const float* row = &sW[r32 + 32 * (it)][0]; \
        const float4 q0 = *reinterpret_cast<const float4*>(row); \
        const float4 q1 = *reinterpret_cast<const float4*>(row + 4); \
        const float4 q2 = *reinterpret_cast<const float4*>(row + 8); \
        const float4 q3 = *reinterpret_cast<const float4*>(row + 12); \
        const float2 q4 = *reinterpret_cast<const float2*>(row + 16); \
        const float f = f##it; \
        a0  = fmaf(f, q0.x, a0);  a1  = fmaf(f, q0.y, a1);  \
        a2  = fmaf(f, q0.z, a2);  a3  = fmaf(f, q0.w, a3);  \
        a4  = fmaf(f, q1.x, a4);  a5  = fmaf(f, q1.y, a5);  \
        a6  = fmaf(f, q1.z, a6);  a7  = fmaf(f, q1.w, a7);  \
        a8  = fmaf(f, q2.x, a8);  a9  = fmaf(f, q2.y, a9);  \
        a10 = fmaf(f, q2.z, a10); a11 = fmaf(f, q2.w, a11); \
        a12 = fmaf(f, q3.x, a12); a13 = fmaf(f, q3.y, a13); \
        a14 = fmaf(f, q3.z, a14); a15 = fmaf(f, q3.w, a15); \
        a16 = fmaf(f, q4.x, a16); a17 = fmaf(f, q4.y, a17); }
    E3(ROWF)

    // reduce lanes with stride 8 (same column) within the wave
#define WRED(j) { a##j += __shfl_down(a##j, 32, 64); a##j += __shfl_down(a##j, 16, 64); \
                  a##j += __shfl_down(a##j, 8, 64); }
    E18(WRED)
    if (lane < 8) {
#define SSTORE(j) sRed[wave][lane][j] = a##j;
        E18(SSTORE)
    }
    __syncthreads();
    if (tid < 8 * kNC) {
        int c = tid / kNC, j = tid - c * kNC;
        int wc = sCol[c];
        if (wc >= 0) {
            float s = sRed[0][c][j] + sRed[1][c][j] + sRed[2][c][j] + sRed[3][c][j];
            float* Pp = (pass == 0) ? Pa_part : Pq_part;
            Pp[((size_t)chunk * kB * kW + (size_t)b * kW + wc) * kNC + j] = s;
        }
    }
}

// --------------------------------------------------------------------------
// K2: dense reduce of the 32 chunk-partials where the PARALLELISM is:
// 216 blocks x 256 threads, each output = 32 independent coalesced loads,
// all L2-resident (7 MB total). P[n] = sum_c P_part[c*kN + n].
// --------------------------------------------------------------------------
__global__ __launch_bounds__(256)
void reduce_kernel(const float* __restrict__ Pa_part, const float* __restrict__ Pq_part,
                   float* __restrict__ Pa, float* __restrict__ Pq) {
    int idx = blockIdx.x * 256 + threadIdx.x;
    if (idx >= 2 * kN) return;
    const float* src = (idx < kN) ? Pa_part : Pq_part;
    float* dst = (idx < kN) ? Pa : Pq;
    int n = (idx < kN) ? idx : idx - kN;
    float s = 0.0f;
#pragma unroll
    for (int c = 0; c < NCH; ++c) s += src[(size_t)c * kN + n];
    dst[n] = s;
}

// --------------------------------------------------------------------------
// K3: per acquiring column wi: heat = mean over wc in [left,right) of the
// 3-layer MLP + sigmoid. Stages DENSE Pa[left..right) into LDS (one load
// per element, 19-float padded rows -> conflict-free) and broadcasts the
// output column. Ballot mask bounds, no barrier-tree.
// --------------------------------------------------------------------------
__global__ __launch_bounds__(256)
void pair_kernel(const float* __restrict__ Pq, const float* __restrict__ Pa,
                 const float* __restrict__ am, const float* __restrict__ qmask,
                 const float* __restrict__ b1, const float* __restrict__ W2,
                 const float* __restrict__ b2, const float* __restrict__ W3,
                 const float* __restrict__ b3, const float* __restrict__ W4,
                 const float* __restrict__ b4, float* __restrict__ out) {
    int wi = blockIdx.x, b = blockIdx.y, tid = threadIdx.x;
    if (!(qmask[b * kW + wi] > 0.0f)) return;

    int lane = tid & 63, wave = tid >> 6;
    int left, right;
    mask_bounds(am + b * kW, lane, &left, &right);
    int span = right - left;

    __shared__ float sPa[kW][19];                               // pad 19 -> conflict-free
    __shared__ float2 sW2[kNC * kNC / 2], sW3[kNC * kNC / 2];   // row-major pairs
    __shared__ float sW4[kNC], sb1[kNC], sb2[kNC], sb3[kNC], sPq[kNC];
    __shared__ float sb4s, wred[4], sHeat;

    if (tid < kNC * kNC / 2) {
        sW2[tid] = reinterpret_cast<const float2*>(W2)[tid];
        sW3[tid] = reinterpret_cast<const float2*>(W3)[tid];
    }
    if (tid >= 192 && tid < 192 + kNC) {
        int j = tid - 192;
        sPq[j] = Pq[((size_t)(b * kW + wi)) * kNC + j];
        sW4[j] = W4[j]; sb1[j] = b1[j]; sb2[j] = b2[j]; sb3[j] = b3[j];
    }
    if (tid == 255) sb4s = b4[0];

    // stage dense Pa[left..right): ~14 independent coalesced loads/thread
    for (int t = tid; t < span * kNC; t += 256) {
        int k = t / kNC, j = t - k * kNC;
        sPa[k][j] = Pa[((size_t)(b * kW + left + k)) * kNC + j];
    }
    __syncthreads();

#define DOT2(S, k, v) (S[(k)*9+0].x*v##0  + S[(k)*9+0].y*v##1  + \
                       S[(k)*9+1].x*v##2  + S[(k)*9+1].y*v##3  + \
                       S[(k)*9+2].x*v##4  + S[(k)*9+2].y*v##5  + \
                       S[(k)*9+3].x*v##6  + S[(k)*9+3].y*v##7  + \
                       S[(k)*9+4].x*v##8  + S[(k)*9+4].y*v##9  + \
                       S[(k)*9+5].x*v##10 + S[(k)*9+5].y*v##11 + \
                       S[(k)*9+6].x*v##12 + S[(k)*9+6].y*v##13 + \
                       S[(k)*9+7].x*v##14 + S[(k)*9+7].y*v##15 + \
                       S[(k)*9+8].x*v##16 + S[(k)*9+8].y*v##17)

    float ssum = 0.0f;
    for (int k = tid; k < span; k += 256) {
        const float* pa = &sPa[k][0];
#define L1(j) float x##j = fmaxf(sPq[j] + sb1[j] + pa[j], 0.0f);
        E18(L1)
        asm volatile("" ::: "memory");
#define L2(k) float y##k = fmaxf(sb2[k] + DOT2(sW2, k, x), 0.0f);
        E18(L2)
        asm volatile("" ::: "memory");
#define L3(k) float z##k = fmaxf(sb3[k] + DOT2(sW3, k, y), 0.0f);
        E18(L3)
        asm volatile("" ::: "memory");
        float t = sb4s +
            (sW4[0]*z0 + sW4[1]*z1 + sW4[2]*z2 + sW4[3]*z3 + sW4[4]*z4 + sW4[5]*z5 +
             sW4[6]*z6 + sW4[7]*z7 + sW4[8]*z8 + sW4[9]*z9 + sW4[10]*z10 + sW4[11]*z11 +
             sW4[12]*z12 + sW4[13]*z13 + sW4[14]*z14 + sW4[15]*z15 + sW4[16]*z16 + sW4[17]*z17);
        ssum += 1.0f / (1.0f + expf(-t));
    }

    ssum += __shfl_down(ssum, 32, 64); ssum += __shfl_down(ssum, 16, 64);
    ssum += __shfl_down(ssum,  8, 64); ssum += __shfl_down(ssum,  4, 64);
    ssum += __shfl_down(ssum,  2, 64); ssum += __shfl_down(ssum,  1, 64);
    if (lane == 0) wred[wave] = ssum;
    __syncthreads();
    if (tid == 0)
        sHeat = (wred[0] + wred[1] + wred[2] + wred[3]) / (float)span;
    __syncthreads();

    // fused output broadcast for this acquiring column
    float hv = sHeat;
    for (int h = tid; h < kH; h += 256)
        out[((size_t)b * kH + h) * kW + wi] = hv;
}

extern "C" void kernel_launch(void* const* d_in, const int* in_sizes, int n_in,
                              void* d_out, int out_size, void* d_ws, size_t ws_size,
                              hipStream_t stream) {
    const float* acquired       = (const float*)d_in[0];
    const float* acquiring      = (const float*)d_in[1];
    const float* acquired_mask  = (const float*)d_in[2];
    const float* acquiring_mask = (const float*)d_in[3];
    const float* W1 = (const float*)d_in[4];
    const float* b1 = (const float*)d_in[5];
    const float* W2 = (const float*)d_in[6];
    const float* b2 = (const float*)d_in[7];
    const float* W3 = (const float*)d_in[8];
    const float* b3 = (const float*)d_in[9];
    const float* W4 = (const float*)d_in[10];
    const float* b4 = (const float*)d_in[11];
    float* out = (float*)d_out;

    float* Pa_part = (float*)d_ws;                 // NCH * kN
    float* Pq_part = Pa_part + (size_t)NCH * kN;   // NCH * kN
    float* Pa      = Pq_part + (size_t)NCH * kN;   // kN
    float* Pq      = Pa + kN;                      // kN

    proj_kernel<<<dim3(NGRP, 2 * NCH, kB), 256, 0, stream>>>(
        acquired, acquiring, acquired_mask, acquiring_mask, W1, Pq_part, Pa_part, out);
    reduce_kernel<<<(2 * kN + 255) / 256, 256, 0, stream>>>(Pa_part, Pq_part, Pa, Pq);
    pair_kernel<<<dim3(kW, kB), 256, 0, stream>>>(
        Pq, Pa, acquired_mask, acquiring_mask,
        b1, W2, b2, W3, b3, W4, b4, out);
}

// Round 6
// 145.089 us; speedup vs baseline: 1.4015x; 1.0541x over previous
//
#include <hip/hip_runtime.h>
#include <math.h>
#include <limits.h>

#define kB 4
#define kC 8
#define kH 384
#define kW 384
#define kCH (kC * kH)   // 3072
#define kIN (2 * kCH)   // 6144
#define kNC 18
#define kMID (kW / 2)

#define NCH 32                // row chunks (96-row chunks)
#define RPC (kCH / NCH)       // 96 rows per chunk
#define CPG 32                // cols per group (256B contiguous k-space reads)
#define NGRP (kW / CPG)       // 12 column groups
#define kN (kB * kW * kNC)    // 27648 floats per dense P array

#define E18(M) M(0) M(1) M(2) M(3) M(4) M(5) M(6) M(7) M(8) M(9) M(10) M(11) M(12) M(13) M(14) M(15) M(16) M(17)
#define E12(M) M(0) M(1) M(2) M(3) M(4) M(5) M(6) M(7) M(8) M(9) M(10) M(11)

// Ballot-based faithful left/right from acquired_mask.
__device__ __forceinline__ void mask_bounds(const float* __restrict__ amb,
                                            int lane, int* left, int* right) {
    unsigned long long mR0 = __ballot(amb[kMID + lane] < 1.0f);
    unsigned long long mR1 = __ballot(amb[kMID + 64 + lane] < 1.0f);
    unsigned long long mR2 = __ballot(amb[kMID + 128 + lane] < 1.0f);
    unsigned long long mL0 = __ballot(amb[kMID - 1 - lane] < 1.0f);
    unsigned long long mL1 = __ballot(amb[kMID - 65 - lane] < 1.0f);
    unsigned long long mL2 = __ballot(amb[kMID - 129 - lane] < 1.0f);
    int candR = mR0 ? __builtin_ctzll(mR0)
              : (mR1 ? 64 + __builtin_ctzll(mR1)
              : (mR2 ? 128 + __builtin_ctzll(mR2) : 0));
    int candL = mL0 ? __builtin_ctzll(mL0)
              : (mL1 ? 64 + __builtin_ctzll(mL1)
              : (mL2 ? 128 + __builtin_ctzll(mL2) : 0));
    *left  = candL + 1;
    *right = kMID + candR;
}

// n-th set bit (0-based) across a 384-bit mask in 6 u64 words; -1 if none.
__device__ __forceinline__ int nth_set(const unsigned long long* m, int n) {
#pragma unroll
    for (int j = 0; j < 6; ++j) {
        int p = __popcll(m[j]);
        if (n < p) {
            unsigned long long x = m[j];
            for (int t = 0; t < n; ++t) x &= (x - 1);   // drop n lowest set bits
            return 64 * j + (int)__builtin_ctzll(x);
        }
        n -= p;
    }
    return -1;
}

// --------------------------------------------------------------------------
// K1: grid (12 col-groups of 32, 64 = chunk|pass, B). 256 threads =
// 32 cols x 8 rows, 12 row-iters (96-row chunk). A wave's k-load touches
// two CONTIGUOUS 256B segments (vs eight scattered 64B lines at 8-col
// groups) -> large DRAM transactions on the dominant pass-0 stream.
// W1 LDS reads are lane-broadcasts (32 lanes same row) -> conflict-free.
// pass 0 = acquired band cols; pass 1 = acquiring cols, ballot-compacted
// (16 active < 32 -> single group). Fused output zero-fill for qm==0.
// --------------------------------------------------------------------------
__global__ __launch_bounds__(256)
void proj_kernel(const float* __restrict__ acquired,
                 const float* __restrict__ acquiring,
                 const float* __restrict__ am,
                 const float* __restrict__ qm,
                 const float* __restrict__ W1,
                 float* __restrict__ Pq_part, float* __restrict__ Pa_part,
                 float* __restrict__ out) {
    int g = blockIdx.x;
    int chunk = blockIdx.y & (NCH - 1);
    int pass = blockIdx.y >> 5;        // 0 = acquired (band), 1 = acquiring
    int b = blockIdx.z;
    int tid = threadIdx.x;
    int r0 = chunk * RPC;

    // ---- fused output zero-fill (poison-safe: pair_kernel writes qm>0 cols)
    {
        int flatB = (blockIdx.z * gridDim.y + blockIdx.y) * gridDim.x + blockIdx.x;
        int gid = flatB * 256 + tid;
        if (gid < kB * kH * kW) {
            int w = gid % kW;
            int ob = gid / (kH * kW);
            if (!(qm[ob * kW + w] > 0.0f)) out[gid] = 0.0f;
        }
    }

    int lane = tid & 63;
    int c32 = tid & 31, r8 = tid >> 5;   // col-in-group, row-in-iter (0..7)
    int wave = tid >> 6;

    __shared__ float sW[RPC][20];          // 7680 B
    __shared__ float sRed[4][CPG][kNC];    // 9216 B
    __shared__ int sCol[CPG];

    int wcol;                            // this thread's source column
    bool slot_ok;
    if (pass == 0) {
        int left, right;
        mask_bounds(am + b * kW, lane, &left, &right);
        int w0 = g * CPG;
        if (!((left < w0 + CPG) && (right > w0))) return;
        wcol = w0 + c32;
        slot_ok = true;                  // pair reads only [left,right)
    } else {
        unsigned long long qmm[6];
#pragma unroll
        for (int j = 0; j < 6; ++j)
            qmm[j] = __ballot(qm[b * kW + 64 * j + lane] > 0.0f);
        int totp = 0;
#pragma unroll
        for (int j = 0; j < 6; ++j) totp += __popcll(qmm[j]);
        if (CPG * g >= totp) return;     // no active column in this group
        int found = nth_set(qmm, CPG * g + c32);
        slot_ok = (found >= 0);
        wcol = slot_ok ? found : 0;      // dummy col 0 for inactive slots
    }
    if (tid < CPG) sCol[tid] = slot_ok ? wcol : -1;

    const float* ks = (pass == 0) ? acquired : acquiring;
    const float* w1 = (pass == 0) ? (W1 + kCH) : W1;  // acquired->W1[:,CH:], acquiring->W1[:,:CH]

    // ---- hoist all k-space loads (rows r8 + 8*it), 256B contiguous per row
    const float* colp = ks + ((size_t)(b * kCH + r0 + r8) * kW + wcol) * 2;
#define KLOAD(it) const float2 v##it = *reinterpret_cast<const float2*>(colp + (size_t)(it) * 8 * kW * 2);
    E12(KLOAD)

    // ---- stage W1 chunk, scalar coalesced loads (overlap with k-loads in flight)
    for (int t = tid; t < kNC * RPC; t += 256) {
        int j = t / RPC, i = t - j * RPC;
        sW[i][j] = w1[j * kIN + r0 + i];
    }
    __syncthreads();

#define KMAG(it) const float f##it = sqrtf(v##it.x * v##it.x + v##it.y * v##it.y);
    E12(KMAG)

#define PDECL(j) float a##j = 0.0f;
    E18(PDECL)

#define ROWF(it) { \
        const float* row = &sW[r8 + 8 * (it)][0]; \
        const float4 q0 = *reinterpret_cast<const float4*>(row); \
        const float4 q1 = *reinterpret_cast<const float4*>(row + 4); \
        const float4 q2 = *reinterpret_cast<const float4*>(row + 8); \
        const float4 q3 = *reinterpret_cast<const float4*>(row + 12); \
        const float2 q4 = *reinterpret_cast<const float2*>(row + 16); \
        const float f = f##it; \
        a0  = fmaf(f, q0.x, a0);  a1  = fmaf(f, q0.y, a1);  \
        a2  = fmaf(f, q0.z, a2);  a3  = fmaf(f, q0.w, a3);  \
        a4  = fmaf(f, q1.x, a4);  a5  = fmaf(f, q1.y, a5);  \
        a6  = fmaf(f, q1.z, a6);  a7  = fmaf(f, q1.w, a7);  \
        a8  = fmaf(f, q2.x, a8);  a9  = fmaf(f, q2.y, a9);  \
        a10 = fmaf(f, q2.z, a10); a11 = fmaf(f, q2.w, a11); \
        a12 = fmaf(f, q3.x, a12); a13 = fmaf(f, q3.y, a13); \
        a14 = fmaf(f, q3.z, a14); a15 = fmaf(f, q3.w, a15); \
        a16 = fmaf(f, q4.x, a16); a17 = fmaf(f, q4.y, a17); }
    E12(ROWF)

    // threads sharing a column: lane c32 and c32+32 (adjacent row-sets)
#define WRED(j) { a##j += __shfl_down(a##j, 32, 64); }
    E18(WRED)
    if (lane < CPG) {
#define SSTORE(j) sRed[wave][lane][j] = a##j;
        E18(SSTORE)
    }
    __syncthreads();
    for (int t = tid; t < CPG * kNC; t += 256) {
        int c = t / kNC, j = t - c * kNC;
        int wc = sCol[c];
        if (wc >= 0) {
            float s = sRed[0][c][j] + sRed[1][c][j] + sRed[2][c][j] + sRed[3][c][j];
            float* Pp = (pass == 0) ? Pa_part : Pq_part;
            Pp[((size_t)chunk * kB * kW + (size_t)b * kW + wc) * kNC + j] = s;
        }
    }
}

// --------------------------------------------------------------------------
// K2: dense reduce of the 32 chunk-partials where the PARALLELISM is:
// 216 blocks x 256 threads, each output = 32 independent coalesced loads,
// all L2-resident (7 MB total). P[n] = sum_c P_part[c*kN + n].
// --------------------------------------------------------------------------
__global__ __launch_bounds__(256)
void reduce_kernel(const float* __restrict__ Pa_part, const float* __restrict__ Pq_part,
                   float* __restrict__ Pa, float* __restrict__ Pq) {
    int idx = blockIdx.x * 256 + threadIdx.x;
    if (idx >= 2 * kN) return;
    const float* src = (idx < kN) ? Pa_part : Pq_part;
    float* dst = (idx < kN) ? Pa : Pq;
    int n = (idx < kN) ? idx : idx - kN;
    float s = 0.0f;
#pragma unroll
    for (int c = 0; c < NCH; ++c) s += src[(size_t)c * kN + n];
    dst[n] = s;
}

// --------------------------------------------------------------------------
// K3: per acquiring column wi: heat = mean over wc in [left,right) of the
// 3-layer MLP + sigmoid. Stages DENSE Pa[left..right) into LDS (one load
// per element, 19-float padded rows -> conflict-free) and broadcasts the
// output column. Ballot mask bounds, no barrier-tree.
// --------------------------------------------------------------------------
__global__ __launch_bounds__(256)
void pair_kernel(const float* __restrict__ Pq, const float* __restrict__ Pa,
                 const float* __restrict__ am, const float* __restrict__ qmask,
                 const float* __restrict__ b1, const float* __restrict__ W2,
                 const float* __restrict__ b2, const float* __restrict__ W3,
                 const float* __restrict__ b3, const float* __restrict__ W4,
                 const float* __restrict__ b4, float* __restrict__ out) {
    int wi = blockIdx.x, b = blockIdx.y, tid = threadIdx.x;
    if (!(qmask[b * kW + wi] > 0.0f)) return;

    int lane = tid & 63, wave = tid >> 6;
    int left, right;
    mask_bounds(am + b * kW, lane, &left, &right);
    int span = right - left;

    __shared__ float sPa[kW][19];                               // pad 19 -> conflict-free
    __shared__ float2 sW2[kNC * kNC / 2], sW3[kNC * kNC / 2];   // row-major pairs
    __shared__ float sW4[kNC], sb1[kNC], sb2[kNC], sb3[kNC], sPq[kNC];
    __shared__ float sb4s, wred[4], sHeat;

    if (tid < kNC * kNC / 2) {
        sW2[tid] = reinterpret_cast<const float2*>(W2)[tid];
        sW3[tid] = reinterpret_cast<const float2*>(W3)[tid];
    }
    if (tid >= 192 && tid < 192 + kNC) {
        int j = tid - 192;
        sPq[j] = Pq[((size_t)(b * kW + wi)) * kNC + j];
        sW4[j] = W4[j]; sb1[j] = b1[j]; sb2[j] = b2[j]; sb3[j] = b3[j];
    }
    if (tid == 255) sb4s = b4[0];

    // stage dense Pa[left..right): ~14 independent coalesced loads/thread
    for (int t = tid; t < span * kNC; t += 256) {
        int k = t / kNC, j = t - k * kNC;
        sPa[k][j] = Pa[((size_t)(b * kW + left + k)) * kNC + j];
    }
    __syncthreads();

#define DOT2(S, k, v) (S[(k)*9+0].x*v##0  + S[(k)*9+0].y*v##1  + \
                       S[(k)*9+1].x*v##2  + S[(k)*9+1].y*v##3  + \
                       S[(k)*9+2].x*v##4  + S[(k)*9+2].y*v##5  + \
                       S[(k)*9+3].x*v##6  + S[(k)*9+3].y*v##7  + \
                       S[(k)*9+4].x*v##8  + S[(k)*9+4].y*v##9  + \
                       S[(k)*9+5].x*v##10 + S[(k)*9+5].y*v##11 + \
                       S[(k)*9+6].x*v##12 + S[(k)*9+6].y*v##13 + \
                       S[(k)*9+7].x*v##14 + S[(k)*9+7].y*v##15 + \
                       S[(k)*9+8].x*v##16 + S[(k)*9+8].y*v##17)

    float ssum = 0.0f;
    for (int k = tid; k < span; k += 256) {
        const float* pa = &sPa[k][0];
#define L1(j) float x##j = fmaxf(sPq[j] + sb1[j] + pa[j], 0.0f);
        E18(L1)
        asm volatile("" ::: "memory");
#define L2(k) float y##k = fmaxf(sb2[k] + DOT2(sW2, k, x), 0.0f);
        E18(L2)
        asm volatile("" ::: "memory");
#define L3(k) float z##k = fmaxf(sb3[k] + DOT2(sW3, k, y), 0.0f);
        E18(L3)
        asm volatile("" ::: "memory");
        float t = sb4s +
            (sW4[0]*z0 + sW4[1]*z1 + sW4[2]*z2 + sW4[3]*z3 + sW4[4]*z4 + sW4[5]*z5 +
             sW4[6]*z6 + sW4[7]*z7 + sW4[8]*z8 + sW4[9]*z9 + sW4[10]*z10 + sW4[11]*z11 +
             sW4[12]*z12 + sW4[13]*z13 + sW4[14]*z14 + sW4[15]*z15 + sW4[16]*z16 + sW4[17]*z17);
        ssum += 1.0f / (1.0f + expf(-t));
    }

    ssum += __shfl_down(ssum, 32, 64); ssum += __shfl_down(ssum, 16, 64);
    ssum += __shfl_down(ssum,  8, 64); ssum += __shfl_down(ssum,  4, 64);
    ssum += __shfl_down(ssum,  2, 64); ssum += __shfl_down(ssum,  1, 64);
    if (lane == 0) wred[wave] = ssum;
    __syncthreads();
    if (tid == 0)
        sHeat = (wred[0] + wred[1] + wred[2] + wred[3]) / (float)span;
    __syncthreads();

    // fused output broadcast for this acquiring column
    float hv = sHeat;
    for (int h = tid; h < kH; h += 256)
        out[((size_t)b * kH + h) * kW + wi] = hv;
}

extern "C" void kernel_launch(void* const* d_in, const int* in_sizes, int n_in,
                              void* d_out, int out_size, void* d_ws, size_t ws_size,
                              hipStream_t stream) {
    const float* acquired       = (const float*)d_in[0];
    const float* acquiring      = (const float*)d_in[1];
    const float* acquired_mask  = (const float*)d_in[2];
    const float* acquiring_mask = (const float*)d_in[3];
    const float* W1 = (const float*)d_in[4];
    const float* b1 = (const float*)d_in[5];
    const float* W2 = (const float*)d_in[6];
    const float* b2 = (const float*)d_in[7];
    const float* W3 = (const float*)d_in[8];
    const float* b3 = (const float*)d_in[9];
    const float* W4 = (const float*)d_in[10];
    const float* b4 = (const float*)d_in[11];
    float* out = (float*)d_out;

    float* Pa_part = (float*)d_ws;                 // NCH * kN
    float* Pq_part = Pa_part + (size_t)NCH * kN;   // NCH * kN
    float* Pa      = Pq_part + (size_t)NCH * kN;   // kN
    float* Pq      = Pa + kN;                      // kN

    proj_kernel<<<dim3(NGRP, 2 * NCH, kB), 256, 0, stream>>>(
        acquired, acquiring, acquired_mask, acquiring_mask, W1, Pq_part, Pa_part, out);
    reduce_kernel<<<(2 * kN + 255) / 256, 256, 0, stream>>>(Pa_part, Pq_part, Pa, Pq);
    pair_kernel<<<dim3(kW, kB), 256, 0, stream>>>(
        Pq, Pa, acquired_mask, acquiring_mask,
        b1, W2, b2, W3, b3, W4, b4, out);
}